// Round 3
// baseline (134.763 us; speedup 1.0000x reference)
//
#include <hip/hip_runtime.h>

// YOLO loss on MI355X. Inputs: yhat (N,52,52,255) f32, y (N,52,52,255) f32,
// anchors (3,3,2) f32, epoch (ignored: epoch=1 >= EPOCH_PRIOR=0 -> prior=0).
// Outputs: concat [coord(N), class(N), noobj(N), obj(N), prior(1)] f32.
//
// R2: single-phase memory access. Stage 16 cells x 255 floats of BOTH tensors
// into LDS via aligned float4 (block base 16320B = 16B aligned, 1020 float4
// exactly), then compute entirely from LDS (fast log/rcp from R1). This
// removes the sel-dependent second global round-trip that made R1
// latency-bound (all pipes <40%).

constexpr int SD      = 52;
constexpr int S2CELLS = SD * SD;        // 2704
constexpr int CH      = 255;            // (5+80)*3
constexpr int CPB     = 16;             // cells per block (4 waves x 4 groups)
constexpr int F4PB    = CPB * CH / 4;   // 1020 float4 per tensor per block
constexpr float EPSF  = 1e-6f;

__device__ __forceinline__ float flog(float x) {
    return __builtin_amdgcn_logf(x) * 0.69314718055994531f;  // v_log_f32 * ln2
}
__device__ __forceinline__ float frcp(float x) {
    return __builtin_amdgcn_rcpf(x);
}

__global__ __launch_bounds__(256) void yolo_loss_kernel(
    const float* __restrict__ yhat, const float* __restrict__ yt,
    const float* __restrict__ anchors, float* __restrict__ out, int N)
{
    __shared__ float4 shA4[F4PB];
    __shared__ float4 shT4[F4PB];
    __shared__ float red[4][4];
    const float* shA = (const float*)shA4;
    const float* shT = (const float*)shT4;

    const int tid  = threadIdx.x;
    const int wv   = tid >> 6;
    const int lane = tid & 63;
    const int grp  = lane >> 4;
    const int sub  = lane & 15;
    const int cellLocal = wv * 4 + grp;

    // ---- stage: both tensors, pure float4, fully coalesced, one phase ----
    const float4* __restrict__ gA4 = (const float4*)(yhat + (size_t)blockIdx.x * (CPB * CH));
    const float4* __restrict__ gT4 = (const float4*)(yt   + (size_t)blockIdx.x * (CPB * CH));
#pragma unroll
    for (int k = 0; k < 4; k++) {
        int e = tid + k * 256;
        if (e < F4PB) {            // last iter: 252 of 256 threads
            shA4[e] = gA4[e];
            shT4[e] = gT4[e];
        }
    }

    // per-cell constants while loads are in flight
    const int cellGlobal = blockIdx.x * CPB + cellLocal;
    const int n       = cellGlobal / S2CELLS;
    const int cellImg = cellGlobal - n * S2CELLS;
    const int irow    = cellImg / SD;
    const int jcol    = cellImg - irow * SD;
    const float jf   = (float)jcol;
    const float if_  = (float)irow;
    const float invS = 1.0f / (float)SD;

    // anchors[scale_idx=2][b][wh] -> flat offset 12 + 2b
    const float aw0 = anchors[12], ah0 = anchors[13];
    const float aw1 = anchors[14], ah1 = anchors[15];
    const float aw2 = anchors[16], ah2 = anchors[17];
    const float rw0 = frcp(aw0), rh0 = frcp(ah0);
    const float rw1 = frcp(aw1), rh1 = frcp(ah1);
    const float rw2 = frcp(aw2), rh2 = frcp(ah2);

    __syncthreads();

    const float* A = shA + cellLocal * CH;
    const float* T = shT + cellLocal * CH;

    // ---- box phase (group-broadcast LDS reads: free) ----
    float hx1[3], hx2[3], hy1[3], hy2[3], ha[3], hcf[3], hw[3], hh[3];
    float tx1[3], tx2[3], ty1[3], ty2[3], ta[3], tcf[3], tw[3], th[3];
    float hxr[3], hyr[3], txr[3], tyr[3];
#pragma unroll
    for (int b = 0; b < 3; b++) {
        const float* p = &A[b * 85];
        float x = p[0], yy = p[1], w = p[2], h = p[3];
        hxr[b] = x; hyr[b] = yy; hw[b] = w; hh[b] = h; hcf[b] = p[4];
        float cx = (x + jf) * invS, cy = (yy + if_) * invS;
        hx1[b] = cx - 0.5f * w; hx2[b] = cx + 0.5f * w;
        hy1[b] = cy - 0.5f * h; hy2[b] = cy + 0.5f * h;
        ha[b]  = (hx2[b] - hx1[b]) * (hy2[b] - hy1[b]);
    }
#pragma unroll
    for (int b = 0; b < 3; b++) {
        const float* p = &T[b * 85];
        float x = p[0], yy = p[1], w = p[2], h = p[3];
        txr[b] = x; tyr[b] = yy; tw[b] = w; th[b] = h; tcf[b] = p[4];
        float cx = (x + jf) * invS, cy = (yy + if_) * invS;
        tx1[b] = cx - 0.5f * w; tx2[b] = cx + 0.5f * w;
        ty1[b] = cy - 0.5f * h; ty2[b] = cy + 0.5f * h;
        ta[b]  = (tx2[b] - tx1[b]) * (ty2[b] - ty1[b]);
    }

    float iou[3][3];
#pragma unroll
    for (int bp = 0; bp < 3; bp++) {
#pragma unroll
        for (int bt = 0; bt < 3; bt++) {
            float wi = fminf(hx2[bp], tx2[bt]) - fmaxf(hx1[bp], tx1[bt]);
            wi = fmaxf(wi, 0.0f);
            float hi = fminf(hy2[bp], ty2[bt]) - fmaxf(hy1[bp], ty1[bt]);
            hi = fmaxf(hi, 0.0f);
            float inter = wi * hi;
            float uni   = ha[bp] + ta[bt] - inter;
            iou[bp][bt] = inter * frcp(uni + EPSF);
        }
    }

    // no-obj (target 0, NO_OBJ_V3)
    float noobj_c = 0.0f;
#pragma unroll
    for (int bp = 0; bp < 3; bp++) {
        float m = fmaxf(fmaxf(iou[bp][0], iou[bp][1]), iou[bp][2]);
        noobj_c += (m < 0.7f) ? hcf[bp] * hcf[bp] : 0.0f;
    }

    // argmax over pred boxes per target (first-max ties, like jnp.argmax)
    int sel[3];
#pragma unroll
    for (int bt = 0; bt < 3; bt++) {
        int s = 0; float v = iou[0][bt];
        if (iou[1][bt] > v) { v = iou[1][bt]; s = 1; }
        if (iou[2][bt] > v) { s = 2; }
        sel[bt] = s;
    }

    float coord_c = 0.0f, obj_c = 0.0f;
    float ho[3];
#pragma unroll
    for (int bt = 0; bt < 3; bt++) {
        int sp = sel[bt];
        float hoo = (tcf[bt] > 0.0f) ? 1.0f : 0.0f;
        ho[bt] = hoo;
        float phx = (sp == 0) ? hxr[0] : ((sp == 1) ? hxr[1] : hxr[2]);
        float phy = (sp == 0) ? hyr[0] : ((sp == 1) ? hyr[1] : hyr[2]);
        float phw = (sp == 0) ? hw[0]  : ((sp == 1) ? hw[1]  : hw[2]);
        float phh = (sp == 0) ? hh[0]  : ((sp == 1) ? hh[1]  : hh[2]);
        float phc = (sp == 0) ? hcf[0] : ((sp == 1) ? hcf[1] : hcf[2]);
        float rwp = (sp == 0) ? rw0 : ((sp == 1) ? rw1 : rw2);
        float rhp = (sp == 0) ? rh0 : ((sp == 1) ? rh1 : rh2);
        float rwt = (bt == 0) ? rw0 : ((bt == 1) ? rw1 : rw2);
        float rht = (bt == 0) ? rh0 : ((bt == 1) ? rh1 : rh2);
        float dx = phx - txr[bt];
        float dy = phy - tyr[bt];
        float dlw = flog(phw * rwp + EPSF) - flog(tw[bt] * rwt + EPSF);
        float dlh = flog(phh * rhp + EPSF) - flog(th[bt] * rht + EPSF);
        float csum = dx * dx + dy * dy + dlw * dlw + dlh * dlh;
        coord_c += csum * hoo * (2.0f - tw[bt] * th[bt]);
        float dcf = phc - tcf[bt];
        obj_c += dcf * dcf * hoo;
    }

    // ---- class loss from LDS: 80 classes x 3 boxes over 16 lanes ----
    float class_c = 0.0f;
#pragma unroll
    for (int b = 0; b < 3; b++) {
        int sp = sel[b];
        const float* pa = A + sp * 85 + 5;
        const float* pt = T + b  * 85 + 5;
        float s = 0.0f;
#pragma unroll
        for (int k = 0; k < 5; k++) {
            int c = sub + k * 16;   // covers 0..79
            float d = pa[c] - pt[c];
            s += d * d;
        }
        class_c += s * ho[b];
    }

    // ---- reductions ----
    class_c += __shfl_xor(class_c, 1, 64);
    class_c += __shfl_xor(class_c, 2, 64);
    class_c += __shfl_xor(class_c, 4, 64);
    class_c += __shfl_xor(class_c, 8, 64);
    if (sub != 0) { coord_c = 0.f; class_c = 0.f; noobj_c = 0.f; obj_c = 0.f; }
    coord_c += __shfl_xor(coord_c, 16, 64); coord_c += __shfl_xor(coord_c, 32, 64);
    class_c += __shfl_xor(class_c, 16, 64); class_c += __shfl_xor(class_c, 32, 64);
    noobj_c += __shfl_xor(noobj_c, 16, 64); noobj_c += __shfl_xor(noobj_c, 32, 64);
    obj_c   += __shfl_xor(obj_c,   16, 64); obj_c   += __shfl_xor(obj_c,   32, 64);

    if (lane == 0) {
        red[wv][0] = coord_c; red[wv][1] = class_c;
        red[wv][2] = noobj_c; red[wv][3] = obj_c;
    }
    __syncthreads();
    if (tid < 4) {
        float s = red[0][tid] + red[1][tid] + red[2][tid] + red[3][tid];
        atomicAdd(&out[tid * N + n], s);
    }
}

extern "C" void kernel_launch(void* const* d_in, const int* in_sizes, int n_in,
                              void* d_out, int out_size, void* d_ws, size_t ws_size,
                              hipStream_t stream) {
    const float* yhat = (const float*)d_in[0];
    const float* yv   = (const float*)d_in[1];
    const float* anc  = (const float*)d_in[2];
    float* out = (float*)d_out;

    const int N = in_sizes[0] / (S2CELLS * CH);

    hipMemsetAsync(d_out, 0, (size_t)out_size * sizeof(float), stream);

    dim3 grid((N * S2CELLS) / CPB);
    yolo_loss_kernel<<<grid, 256, 0, stream>>>(yhat, yv, anc, out, N);
}

// Round 4
// 78.499 us; speedup vs baseline: 1.7167x; 1.7167x over previous
//
#include <hip/hip_runtime.h>

// YOLO loss on MI355X. Inputs: yhat (N,52,52,255) f32, y (N,52,52,255) f32,
// anchors (3,3,2) f32, epoch (ignored: epoch=1 >= EPOCH_PRIOR=0 -> prior=0).
// Outputs: concat [coord(N), class(N), noobj(N), obj(N), prior(1)] f32.
//
// R3: persistent blocks. 16 blocks per image, each loops over ~10-11 chunks of
// 16 cells (one cell per 16-lane group), accumulating the 4 losses in
// registers. No LDS staging, no barriers/atomics in the loop. All loads of an
// iteration (box + ALL 6 class blocks) issue before any compute; the argmax
// selection gathers VALUES via cndmask, not addresses -> single memory
// latency exposure per iteration, ~60 loads in flight.

constexpr int SD      = 52;
constexpr int S2CELLS = SD * SD;        // 2704
constexpr int CH      = 255;            // (5+80)*3
constexpr int CPB     = 16;             // cells per chunk (4 waves x 4 groups)
constexpr int BIMG    = 16;             // blocks per image
constexpr int CHUNKS  = S2CELLS / CPB;  // 169
constexpr float EPSF  = 1e-6f;

__device__ __forceinline__ float flog(float x) {
    return __builtin_amdgcn_logf(x) * 0.69314718055994531f;  // v_log_f32 * ln2
}
__device__ __forceinline__ float frcp(float x) {
    return __builtin_amdgcn_rcpf(x);
}
__device__ __forceinline__ float sel3(int s, float a, float b, float c) {
    return (s == 0) ? a : ((s == 1) ? b : c);   // 2x v_cndmask
}

__global__ __launch_bounds__(256, 4) void yolo_loss_kernel(
    const float* __restrict__ yhat, const float* __restrict__ yt,
    const float* __restrict__ anchors, float* __restrict__ out, int N)
{
    __shared__ float red[4][4];

    const int tid  = threadIdx.x;
    const int wv   = tid >> 6;
    const int lane = tid & 63;
    const int grp  = lane >> 4;
    const int sub  = lane & 15;
    const int cellLocal = wv * 4 + grp;

    const int n   = blockIdx.x >> 4;          // image index (BIMG = 16)
    const int blk = blockIdx.x & (BIMG - 1);  // block within image

    // anchors[scale_idx=2][b][wh] -> flat offset 12 + 2b
    const float aw0 = anchors[12], ah0 = anchors[13];
    const float aw1 = anchors[14], ah1 = anchors[15];
    const float aw2 = anchors[16], ah2 = anchors[17];
    const float rw0 = frcp(aw0), rh0 = frcp(ah0);
    const float rw1 = frcp(aw1), rh1 = frcp(ah1);
    const float rw2 = frcp(aw2), rh2 = frcp(ah2);
    const float invS = 1.0f / (float)SD;

    float acc_coord = 0.f, acc_class = 0.f, acc_noobj = 0.f, acc_obj = 0.f;

    const size_t imgBase = (size_t)n * S2CELLS * CH;

    for (int c = blk; c < CHUNKS; c += BIMG) {
        const int cellImg = c * CPB + cellLocal;
        const float* __restrict__ A = yhat + imgBase + (size_t)cellImg * CH;
        const float* __restrict__ T = yt   + imgBase + (size_t)cellImg * CH;

        // ---- ALL loads first (addresses independent of any compute) ----
        float av[3][5], tv[3][5];     // box: x,y,w,h,conf (group-broadcast)
        float acv[3][5], tcv[3][5];   // class: lane sub covers c = sub+16k
#pragma unroll
        for (int b = 0; b < 3; b++)
#pragma unroll
            for (int k = 0; k < 5; k++) {
                av[b][k] = A[b * 85 + k];
                tv[b][k] = T[b * 85 + k];
            }
#pragma unroll
        for (int b = 0; b < 3; b++)
#pragma unroll
            for (int k = 0; k < 5; k++) {
                int cc = b * 85 + 5 + sub + k * 16;
                acv[b][k] = A[cc];
                tcv[b][k] = T[cc];
            }

        const int irow = cellImg / SD;
        const int jcol = cellImg - irow * SD;
        const float jf = (float)jcol, if_ = (float)irow;

        // ---- box geometry ----
        float hx1[3], hx2[3], hy1[3], hy2[3], ha[3];
        float tx1[3], tx2[3], ty1[3], ty2[3], ta[3];
#pragma unroll
        for (int b = 0; b < 3; b++) {
            float w = av[b][2], h = av[b][3];
            float cx = (av[b][0] + jf) * invS, cy = (av[b][1] + if_) * invS;
            hx1[b] = cx - 0.5f * w; hx2[b] = cx + 0.5f * w;
            hy1[b] = cy - 0.5f * h; hy2[b] = cy + 0.5f * h;
            ha[b]  = (hx2[b] - hx1[b]) * (hy2[b] - hy1[b]);
        }
#pragma unroll
        for (int b = 0; b < 3; b++) {
            float w = tv[b][2], h = tv[b][3];
            float cx = (tv[b][0] + jf) * invS, cy = (tv[b][1] + if_) * invS;
            tx1[b] = cx - 0.5f * w; tx2[b] = cx + 0.5f * w;
            ty1[b] = cy - 0.5f * h; ty2[b] = cy + 0.5f * h;
            ta[b]  = (tx2[b] - tx1[b]) * (ty2[b] - ty1[b]);
        }

        float iou[3][3];
#pragma unroll
        for (int bp = 0; bp < 3; bp++)
#pragma unroll
            for (int bt = 0; bt < 3; bt++) {
                float wi = fminf(hx2[bp], tx2[bt]) - fmaxf(hx1[bp], tx1[bt]);
                wi = fmaxf(wi, 0.0f);
                float hi = fminf(hy2[bp], ty2[bt]) - fmaxf(hy1[bp], ty1[bt]);
                hi = fmaxf(hi, 0.0f);
                float inter = wi * hi;
                float uni   = ha[bp] + ta[bt] - inter;
                iou[bp][bt] = inter * frcp(uni + EPSF);
            }

        // no-obj (target 0, NO_OBJ_V3)
#pragma unroll
        for (int bp = 0; bp < 3; bp++) {
            float m = fmaxf(fmaxf(iou[bp][0], iou[bp][1]), iou[bp][2]);
            acc_noobj += (m < 0.7f) ? av[bp][4] * av[bp][4] : 0.0f;
        }

        // argmax over pred boxes per target (first-max ties, like jnp.argmax)
        int sel[3];
#pragma unroll
        for (int bt = 0; bt < 3; bt++) {
            int s = 0; float v = iou[0][bt];
            if (iou[1][bt] > v) { v = iou[1][bt]; s = 1; }
            if (iou[2][bt] > v) { s = 2; }
            sel[bt] = s;
        }

        float ho[3];
#pragma unroll
        for (int bt = 0; bt < 3; bt++) {
            int sp = sel[bt];
            float hoo = (tv[bt][4] > 0.0f) ? 1.0f : 0.0f;
            ho[bt] = hoo;
            float phx = sel3(sp, av[0][0], av[1][0], av[2][0]);
            float phy = sel3(sp, av[0][1], av[1][1], av[2][1]);
            float phw = sel3(sp, av[0][2], av[1][2], av[2][2]);
            float phh = sel3(sp, av[0][3], av[1][3], av[2][3]);
            float phc = sel3(sp, av[0][4], av[1][4], av[2][4]);
            float rwp = sel3(sp, rw0, rw1, rw2);
            float rhp = sel3(sp, rh0, rh1, rh2);
            float rwt = (bt == 0) ? rw0 : ((bt == 1) ? rw1 : rw2);
            float rht = (bt == 0) ? rh0 : ((bt == 1) ? rh1 : rh2);
            float dx  = phx - tv[bt][0];
            float dy  = phy - tv[bt][1];
            float dlw = flog(phw * rwp + EPSF) - flog(tv[bt][2] * rwt + EPSF);
            float dlh = flog(phh * rhp + EPSF) - flog(tv[bt][3] * rht + EPSF);
            float csum = dx * dx + dy * dy + dlw * dlw + dlh * dlh;
            acc_coord += csum * hoo * (2.0f - tv[bt][2] * tv[bt][3]);
            float dcf = phc - tv[bt][4];
            acc_obj += dcf * dcf * hoo;
        }

        // class: select VALUES (cndmask), not addresses
#pragma unroll
        for (int bt = 0; bt < 3; bt++) {
            int sp = sel[bt];
            float s = 0.0f;
#pragma unroll
            for (int k = 0; k < 5; k++) {
                float pa = sel3(sp, acv[0][k], acv[1][k], acv[2][k]);
                float d  = pa - tcv[bt][k];
                s += d * d;
            }
            acc_class += s * ho[bt];
        }
    }

    // ---- single final reduction ----
    // coord/noobj/obj are replicated x16 within each group -> scale by 1/16
    // (exact power of two). class is lane-partitioned (no scaling).
#pragma unroll
    for (int off = 1; off < 64; off <<= 1) {
        acc_coord += __shfl_xor(acc_coord, off, 64);
        acc_class += __shfl_xor(acc_class, off, 64);
        acc_noobj += __shfl_xor(acc_noobj, off, 64);
        acc_obj   += __shfl_xor(acc_obj,   off, 64);
    }
    if (lane == 0) {
        red[wv][0] = acc_coord; red[wv][1] = acc_class;
        red[wv][2] = acc_noobj; red[wv][3] = acc_obj;
    }
    __syncthreads();
    if (tid < 4) {
        float s = red[0][tid] + red[1][tid] + red[2][tid] + red[3][tid];
        if (tid != 1) s *= 0.0625f;   // un-replicate coord/noobj/obj
        atomicAdd(&out[tid * N + n], s);
    }
}

extern "C" void kernel_launch(void* const* d_in, const int* in_sizes, int n_in,
                              void* d_out, int out_size, void* d_ws, size_t ws_size,
                              hipStream_t stream) {
    const float* yhat = (const float*)d_in[0];
    const float* yv   = (const float*)d_in[1];
    const float* anc  = (const float*)d_in[2];
    float* out = (float*)d_out;

    const int N = in_sizes[0] / (S2CELLS * CH);

    hipMemsetAsync(d_out, 0, (size_t)out_size * sizeof(float), stream);

    dim3 grid(N * BIMG);
    yolo_loss_kernel<<<grid, 256, 0, stream>>>(yhat, yv, anc, out, N);
}